// Round 1
// 364.585 us; speedup vs baseline: 1.0612x; 1.0612x over previous
//
#include <hip/hip_runtime.h>
#include <hip/hip_bf16.h>
#include <float.h>

#define IN_F 256
#define HD   128   // H*D
#define NH   4
#define GM   128   // gemm rows per tile

typedef __bf16 bf16x8 __attribute__((ext_vector_type(8)));
typedef __bf16 bf16x2 __attribute__((ext_vector_type(2)));
typedef float  f32x4  __attribute__((ext_vector_type(4)));

__device__ __forceinline__ bf16x8 cvt8(const float4 a, const float4 b) {
    bf16x8 r;
    r[0] = (__bf16)a.x; r[1] = (__bf16)a.y; r[2] = (__bf16)a.z; r[3] = (__bf16)a.w;
    r[4] = (__bf16)b.x; r[5] = (__bf16)b.y; r[6] = (__bf16)b.z; r[7] = (__bf16)b.w;
    return r;
}

// ---------------------------------------------------------------------------
// Fused persistent-block kernel:
//   (a) deg/rank atomic count (grid-stride over E) -- overlaps GEMM BW phase
//   (b) MFMA GEMM ft_bf16[N][128] = bf16(feat) @ bf16(W)^T, software-pipelined:
//       A-slice for step k+1 is prefetched to registers BEFORE the visibility
//       barrier of step k, so HBM latency spans barrier+MFMA instead of being
//       serially exposed (old version loaded after the barrier -> ~700cy stall
//       per ks-step, 8x per tile).
//   (c) el/er epilogue fused: acc already holds every (row,col); butterfly
//       shfl_xor over the 16 col-lanes per g-group gives the per-head dots.
// grid=512 (2 blocks/CU; LDS ~78 KB). Wave w owns rows w*32..w*32+31.
// mfma_f32_16x16x32_bf16; C/D: col=lane&15, row=(lane>>4)*4+reg (verified R2).
// ---------------------------------------------------------------------------
__global__ __launch_bounds__(256) void gemm_fused(const float* __restrict__ feat,
                                                  const float* __restrict__ w,
                                                  const float* __restrict__ attn_l,
                                                  const float* __restrict__ attn_r,
                                                  const int* __restrict__ dst,
                                                  __bf16* __restrict__ ft,
                                                  float* __restrict__ el,
                                                  float* __restrict__ er,
                                                  int* __restrict__ deg,
                                                  int* __restrict__ rank,
                                                  int N, int E, int ntiles) {
    __shared__ __align__(16) __bf16 Bs[128][264];  // [col][k], +8 pad
    __shared__ __align__(16) __bf16 As[GM][40];    // [row][k], +8 pad
    const int t = threadIdx.x;
    const int wv = t >> 6;
    const int lane = t & 63;

    // ---- stage all of W as bf16 (once per block) ----
    {
        const int col = t >> 1;
        const int koff = (t & 1) * 128;
        const float* wp = w + (size_t)col * IN_F + koff;
#pragma unroll
        for (int i = 0; i < 128; i += 8) {
            const float4 v0 = *(const float4*)(wp + i);
            const float4 v1 = *(const float4*)(wp + i + 4);
            *(bf16x8*)&Bs[col][koff + i] = cvt8(v0, v1);
        }
    }

    // ---- fused deg/rank atomic phase (independent of GEMM data) ----
    for (int i = blockIdx.x * 256 + t; i < E; i += gridDim.x * 256)
        rank[i] = atomicAdd(&deg[dst[i]], 1);

    const int frow = lane & 15;
    const int fk   = (lane >> 4) * 8;

    // per-lane attn weights for this lane's 8 columns (ct*16+frow)
    float alw[8], arw[8];
#pragma unroll
    for (int ct = 0; ct < 8; ++ct) {
        alw[ct] = attn_l[ct * 16 + frow];
        arw[ct] = attn_r[ct * 16 + frow];
    }

    const int ar_ = t >> 1;          // A-stage row 0..127
    const int ac  = (t & 1) * 16;    // A-stage k-offset {0,16}

    // ---- prefetch slice (tile=blockIdx.x, ks=0) ----
    float4 p0, p1, p2, p3;
    {
        const int gr = blockIdx.x * GM + ar_;
        if (gr < N) {
            const float* fp = feat + (size_t)gr * IN_F + ac;
            p0 = *(const float4*)(fp);
            p1 = *(const float4*)(fp + 4);
            p2 = *(const float4*)(fp + 8);
            p3 = *(const float4*)(fp + 12);
        } else {
            p0 = p1 = p2 = p3 = make_float4(0.f, 0.f, 0.f, 0.f);
        }
    }

    for (int tile = blockIdx.x; tile < ntiles; tile += gridDim.x) {
        const int row0 = tile * GM;
        f32x4 acc[2][8];
#pragma unroll
        for (int mt = 0; mt < 2; ++mt)
#pragma unroll
            for (int ct = 0; ct < 8; ++ct) acc[mt][ct] = {0.f, 0.f, 0.f, 0.f};

        for (int ks = 0; ks < 8; ++ks) {
            __syncthreads();   // A: all waves done reading As from prev step
            *(bf16x8*)&As[ar_][ac]     = cvt8(p0, p1);
            *(bf16x8*)&As[ar_][ac + 8] = cvt8(p2, p3);

            // prefetch next slice (crosses tile boundary at ks==7)
            const int ntile = (ks < 7) ? tile : tile + gridDim.x;
            const int nks   = (ks < 7) ? ks + 1 : 0;
            if (ntile < ntiles) {
                const int gr = ntile * GM + ar_;
                if (gr < N) {
                    const float* fp = feat + (size_t)gr * IN_F + nks * 32 + ac;
                    p0 = *(const float4*)(fp);
                    p1 = *(const float4*)(fp + 4);
                    p2 = *(const float4*)(fp + 8);
                    p3 = *(const float4*)(fp + 12);
                } else {
                    p0 = p1 = p2 = p3 = make_float4(0.f, 0.f, 0.f, 0.f);
                }
            }

            __syncthreads();   // B: As writes visible
            const int k0 = ks * 32;
            const bf16x8 af0 = *(const bf16x8*)&As[wv * 32 + frow][fk];
            const bf16x8 af1 = *(const bf16x8*)&As[wv * 32 + 16 + frow][fk];
#pragma unroll
            for (int ct = 0; ct < 8; ++ct) {
                const bf16x8 bfrag = *(const bf16x8*)&Bs[ct * 16 + frow][k0 + fk];
                acc[0][ct] = __builtin_amdgcn_mfma_f32_16x16x32_bf16(af0, bfrag, acc[0][ct], 0, 0, 0);
                acc[1][ct] = __builtin_amdgcn_mfma_f32_16x16x32_bf16(af1, bfrag, acc[1][ct], 0, 0, 0);
            }
        }

        // ---- epilogue: ft stores ----
        // row = (lane>>4)*4 + reg, col = ct*16 + frow
        const int rb = row0 + wv * 32 + (lane >> 4) * 4;
        if (row0 + GM <= N) {
#pragma unroll
            for (int mt = 0; mt < 2; ++mt)
#pragma unroll
                for (int ct = 0; ct < 8; ++ct)
#pragma unroll
                    for (int reg = 0; reg < 4; ++reg) {
                        const int m = rb + mt * 16 + reg;
                        ft[(size_t)m * HD + ct * 16 + frow] = (__bf16)acc[mt][ct][reg];
                    }
        } else {
#pragma unroll
            for (int mt = 0; mt < 2; ++mt)
#pragma unroll
                for (int ct = 0; ct < 8; ++ct)
#pragma unroll
                    for (int reg = 0; reg < 4; ++reg) {
                        const int m = rb + mt * 16 + reg;
                        if (m < N) ft[(size_t)m * HD + ct * 16 + frow] = (__bf16)acc[mt][ct][reg];
                    }
        }

        // ---- fused el/er epilogue ----
        // el[r][h] = sum over 32 cols of head h = sum_{ct in {2h,2h+1}} acc*alw,
        // reduced over the 16 frow-lanes of this g-group (xor 1,2,4,8 stays in group).
#pragma unroll
        for (int mt = 0; mt < 2; ++mt) {
#pragma unroll
            for (int reg = 0; reg < 4; ++reg) {
                float pl[4], pr[4];
#pragma unroll
                for (int h = 0; h < 4; ++h) {
                    const float v0 = acc[mt][2 * h][reg];
                    const float v1 = acc[mt][2 * h + 1][reg];
                    pl[h] = v0 * alw[2 * h] + v1 * alw[2 * h + 1];
                    pr[h] = v0 * arw[2 * h] + v1 * arw[2 * h + 1];
                }
#pragma unroll
                for (int s = 1; s < 16; s <<= 1) {
#pragma unroll
                    for (int h = 0; h < 4; ++h) {
                        pl[h] += __shfl_xor(pl[h], s);
                        pr[h] += __shfl_xor(pr[h], s);
                    }
                }
                if (frow == 0) {
                    const int r = row0 + wv * 32 + mt * 16 + (lane >> 4) * 4 + reg;
                    if (r < N) {
                        *(float4*)(el + (size_t)r * NH) = make_float4(pl[0], pl[1], pl[2], pl[3]);
                        *(float4*)(er + (size_t)r * NH) = make_float4(pr[0], pr[1], pr[2], pr[3]);
                    }
                }
            }
        }
    }
}

// ---------------------------------------------------------------------------
// CSR build (scan + scatter; deg/rank now produced by gemm_fused)
// ---------------------------------------------------------------------------
__global__ __launch_bounds__(1024) void scan1_k(const int* __restrict__ deg,
                                                int* __restrict__ off,
                                                int* __restrict__ bsum, int N) {
    __shared__ int lds[1024];
    const int t = threadIdx.x;
    const int g = blockIdx.x * 1024 + t;
    const int x = (g < N) ? deg[g] : 0;
    lds[t] = x;
    __syncthreads();
    int v = x;
    for (int s = 1; s < 1024; s <<= 1) {
        const int add = (t >= s) ? lds[t - s] : 0;
        __syncthreads();
        v += add;
        lds[t] = v;
        __syncthreads();
    }
    if (g < N) off[g] = v - x;
    if (t == 1023) bsum[blockIdx.x] = v;
}

__global__ __launch_bounds__(128) void scan2_k(const int* __restrict__ bsum,
                                               int* __restrict__ boff, int nb) {
    __shared__ int lds[128];
    const int t = threadIdx.x;
    const int x = (t < nb) ? bsum[t] : 0;
    lds[t] = x;
    __syncthreads();
    int v = x;
    for (int s = 1; s < 128; s <<= 1) {
        const int add = (t >= s) ? lds[t - s] : 0;
        __syncthreads();
        v += add;
        lds[t] = v;
        __syncthreads();
    }
    boff[t] = v - x;
}

__global__ __launch_bounds__(256) void scatter_k(const int* __restrict__ src,
                                                 const int* __restrict__ dst,
                                                 const int* __restrict__ off,
                                                 const int* __restrict__ boff,
                                                 const int* __restrict__ rank,
                                                 int* __restrict__ ssrc, int E) {
    const int i = blockIdx.x * 256 + threadIdx.x;
    if (i < E) {
        const int d = dst[i];
        const int p = off[d] + boff[d >> 10] + rank[i];
        ssrc[p] = src[i];
    }
}

// ---------------------------------------------------------------------------
// Aggregation: one wave per dst node. Exp phase: 64 edges/chunk, lane j
// computes a=exp(leaky(el[src]+er[n])) (4 heads) -> LDS (zeros for padding).
// Sweep phase: 16 lanes per edge, 4 edges in flight (q = lane>>4 picks the
// edge), each lane loads bf16x8 (16 B) of ft[src]; unrolled x2 -> 8 edges per
// iteration, two independent load chains. Final shfl_xor(16,32) combines the
// four quarter-wave accumulators.  (UNCHANGED from previous round.)
// ---------------------------------------------------------------------------
__global__ __launch_bounds__(64) void aggregate_k(const __bf16* __restrict__ ft,
                                                  const float* __restrict__ el,
                                                  const float* __restrict__ er,
                                                  const int* __restrict__ deg,
                                                  const int* __restrict__ off,
                                                  const int* __restrict__ boff,
                                                  const int* __restrict__ ssrc,
                                                  float* __restrict__ out, int N) {
    const int n = blockIdx.x;
    const int lane = threadIdx.x;
    const int il = lane & 15;       // feature group: f = il*8 .. il*8+7
    const int q  = lane >> 4;       // edge slot within group of 4
    const int h  = il >> 2;         // head of this feature group
    float4* outp = (float4*)(out + (size_t)n * HD);
    const int dn = deg[n];
    if (dn == 0) {
        if (q < 2) outp[il * 2 + q] = make_float4(0.f, 0.f, 0.f, 0.f);
        return;
    }
    const int start = off[n] + boff[n >> 10];
    const float4 er4 = *(const float4*)(er + (size_t)n * NH);

    __shared__ float a_lds[64 * NH];
    __shared__ int   s_lds[64];
    float4 ssum = make_float4(0.f, 0.f, 0.f, 0.f);
    float acc[8];
#pragma unroll
    for (int i = 0; i < 8; ++i) acc[i] = 0.f;

    for (int c0 = 0; c0 < dn; c0 += 64) {
        const int j = c0 + lane;
        float4 a = make_float4(0.f, 0.f, 0.f, 0.f);
        int sv = 0;
        if (j < dn) {
            sv = ssrc[start + j];
            float4 e = *(const float4*)(el + (size_t)sv * NH);
            e.x += er4.x; e.y += er4.y; e.z += er4.z; e.w += er4.w;
            e.x = e.x >= 0.f ? e.x : 0.2f * e.x;
            e.y = e.y >= 0.f ? e.y : 0.2f * e.y;
            e.z = e.z >= 0.f ? e.z : 0.2f * e.z;
            e.w = e.w >= 0.f ? e.w : 0.2f * e.w;
            a.x = __expf(e.x); a.y = __expf(e.y);
            a.z = __expf(e.z); a.w = __expf(e.w);
            ssum.x += a.x; ssum.y += a.y; ssum.z += a.z; ssum.w += a.w;
        }
        s_lds[lane] = sv;
        *(float4*)(a_lds + lane * NH) = a;
        __syncthreads();
        const int cnt = min(64, dn - c0);
        for (int j2 = 0; j2 < cnt; j2 += 8) {   // 8 edges/iter (2 groups of 4)
            const int e0 = j2 + q;
            const int e1 = j2 + 4 + q;
            const int sv0 = s_lds[e0];
            const int sv1 = s_lds[e1];
            const float a0 = a_lds[e0 * NH + h];
            const float a1 = a_lds[e1 * NH + h];
            const bf16x8 f0 = *(const bf16x8*)(ft + (size_t)sv0 * HD + il * 8);
            const bf16x8 f1 = *(const bf16x8*)(ft + (size_t)sv1 * HD + il * 8);
#pragma unroll
            for (int k = 0; k < 8; ++k) acc[k] = fmaf(a0, (float)f0[k], acc[k]);
#pragma unroll
            for (int k = 0; k < 8; ++k) acc[k] = fmaf(a1, (float)f1[k], acc[k]);
        }
        __syncthreads();
    }
#pragma unroll
    for (int s = 1; s < 64; s <<= 1) {
        ssum.x += __shfl_xor(ssum.x, s);
        ssum.y += __shfl_xor(ssum.y, s);
        ssum.z += __shfl_xor(ssum.z, s);
        ssum.w += __shfl_xor(ssum.w, s);
    }
#pragma unroll
    for (int k = 0; k < 8; ++k) {
        acc[k] += __shfl_xor(acc[k], 16);
        acc[k] += __shfl_xor(acc[k], 32);
    }
    const float sumh = (h == 0) ? ssum.x : (h == 1) ? ssum.y : (h == 2) ? ssum.z : ssum.w;
    const float inv = 1.f / sumh;
    if (q < 2) {
        const int b = q * 4;
        outp[il * 2 + q] = make_float4(acc[b] * inv, acc[b + 1] * inv,
                                       acc[b + 2] * inv, acc[b + 3] * inv);
    }
}

// ---------------------------------------------------------------------------
extern "C" void kernel_launch(void* const* d_in, const int* in_sizes, int n_in,
                              void* d_out, int out_size, void* d_ws, size_t ws_size,
                              hipStream_t stream) {
    const float* feat   = (const float*)d_in[0];
    const float* fc_w   = (const float*)d_in[1];
    const float* attn_l = (const float*)d_in[2];
    const float* attn_r = (const float*)d_in[3];
    const int*   src    = (const int*)d_in[4];
    const int*   dst    = (const int*)d_in[5];
    const int N = in_sizes[0] / IN_F;
    const int E = in_sizes[4];
    float* out = (float*)d_out;

    char* wp = (char*)d_ws;
    __bf16* ft = (__bf16*)wp; wp += (size_t)N * HD * 2;  // 25.6 MB
    float* el  = (float*)wp; wp += (size_t)N * NH * 4;   // 1.6 MB
    float* er  = (float*)wp; wp += (size_t)N * NH * 4;   // 1.6 MB
    int* deg   = (int*)wp;   wp += (size_t)N * 4;        // 0.4 MB
    int* off   = (int*)wp;   wp += (size_t)N * 4;        // 0.4 MB
    int* bsum  = (int*)wp;   wp += 1024;
    int* boff  = (int*)wp;   wp += 1024;
    int* rank  = (int*)wp;   wp += (size_t)E * 4;        // 6.4 MB
    int* ssrc  = (int*)wp;   wp += (size_t)E * 4;        // 6.4 MB

    hipMemsetAsync(deg, 0, (size_t)N * 4, stream);

    const int ntiles = (N + GM - 1) / GM;
    gemm_fused<<<dim3(512), dim3(256), 0, stream>>>(feat, fc_w, attn_l, attn_r, dst,
                                                    ft, el, er, deg, rank, N, E, ntiles);
    const int nblk = (N + 1023) >> 10;
    scan1_k<<<dim3(nblk), dim3(1024), 0, stream>>>(deg, off, bsum, N);
    scan2_k<<<dim3(1), dim3(128), 0, stream>>>(bsum, boff, nblk);
    scatter_k<<<dim3((E + 255) / 256), dim3(256), 0, stream>>>(src, dst, off, boff, rank, ssrc, E);
    aggregate_k<<<dim3(N), dim3(64), 0, stream>>>(ft, el, er, deg, off, boff, ssrc, out, N);
}